// Round 7
// baseline (562.782 us; speedup 1.0000x reference)
//
#include <hip/hip_runtime.h>

// CRF forward: B=256, T<=2048, C=64. One block (4 waves) per batch.
// Waves 0-2: PRODUCERS — stream ex[t][j] = 2^(x[t][j]*log2e) into a
//   double-buffered LDS chunk ring (CH=64 steps/chunk, 2 chunks resident).
// Wave 3: CHAIN — single-wave MFMA recurrence (round-6 layout, verified):
//   S_t = E . q_{t-1} via 8 INDEPENDENT mfma_f32_16x16x32_bf16 (4 row-tiles
//   x 2 K-chunks, f32-add join -> depth-1 MFMA), q_t = ex_t * r * S_t with
//   r = rcp(firstlane(S_{t-1}[0])), Mbar -= log2(r) (exact bookkeeping).
//   Chain has zero global loads and zero exp2 in the loop.
// Layout bijection kappa(g,i) = 4g+(i&3)+16*(i>>2) on BOTH A(=exp(trans)) and
// B(=q) makes the D rows a lane holds exactly the B-slots its next fragment
// needs -> lane-local recirculation (8 cvt_pk), no shuffles/LDS for q.
// Sync: raw s_barrier (lgkmcnt-only drain) once per chunk phase.

#define CC 64
#define CH 64
#define NSLOT (2 * CH)   // 128 slots, chunk parity alternates

typedef short bf16x8 __attribute__((ext_vector_type(8)));
typedef float f32x4 __attribute__((ext_vector_type(4)));

union PackAB { int w[4]; bf16x8 v; };

__device__ __forceinline__ int cvtpk(float lo, float hi) {
    int r;
    asm("v_cvt_pk_bf16_f32 %0, %1, %2" : "=v"(r) : "v"(lo), "v"(hi));
    return r;
}
__device__ __forceinline__ float bcast0(float v) {
    return __int_as_float(__builtin_amdgcn_readfirstlane(__float_as_int(v)));
}
// verified (round 5): sum of both permlane*_swap outputs == v[l] + v[l^G]
__device__ __forceinline__ float pairsum16(float v) {
#if __has_builtin(__builtin_amdgcn_permlane16_swap)
    unsigned u = __float_as_uint(v);
    auto r = __builtin_amdgcn_permlane16_swap(u, u, false, false);
    return __uint_as_float(r[0]) + __uint_as_float(r[1]);
#else
    return v + __int_as_float(__builtin_amdgcn_ds_swizzle(__float_as_int(v), 0x401F));
#endif
}
__device__ __forceinline__ float pairsum32(float v, int lane) {
#if __has_builtin(__builtin_amdgcn_permlane32_swap)
    unsigned u = __float_as_uint(v);
    auto r = __builtin_amdgcn_permlane32_swap(u, u, false, false);
    return __uint_as_float(r[0]) + __uint_as_float(r[1]);
#else
    int idx = (lane ^ 32) << 2;
    return v + __int_as_float(__builtin_amdgcn_ds_bpermute(idx, __float_as_int(v)));
#endif
}

#define WG_SYNC() do {                                      \
    asm volatile("s_waitcnt lgkmcnt(0)" ::: "memory");      \
    __builtin_amdgcn_s_barrier();                           \
    asm volatile("" ::: "memory");                          \
} while (0)

__launch_bounds__(256, 1)
__global__ void crf_fwd_kernel(const float* __restrict__ x,      // (B,T,C)
                               const float* __restrict__ trans,  // (C,C)
                               const float* __restrict__ orig,   // (C,)
                               const int*   __restrict__ lens,   // (B,)
                               float* __restrict__ out,          // (B,)
                               int T) {
    const int b   = blockIdx.x;
    const int tid = threadIdx.x;
    const int w   = tid >> 6;
    const int l   = tid & 63;
    const int c   = l & 15, g = l >> 4;
    const float L2E = 1.4426950408889634f, LN2 = 0.6931471805599453f;

    __shared__ float ex_lds[NSLOT][CC];   // 32 KiB

    const int L = lens[b];
    const float* xb = x + (size_t)b * T * CC;
    const int nch = (L > 1) ? ((L - 1) / CH + 1) : 0;

    if (w < 3) {
        // ---------------- producers ----------------
        if (nch > 0) {
            for (int q8 = w; q8 < CH; q8 += 3) {          // chunk 0 (t = 0..63)
                int t = q8;
                int tc = t < T ? t : T - 1;
                ex_lds[t & (NSLOT - 1)][l] =
                    __builtin_amdgcn_exp2f(xb[(size_t)tc * CC + l] * L2E);
            }
            WG_SYNC();
            for (int cph = 0; cph < nch; ++cph) {
                if (cph + 1 < nch) {
                    int base = (cph + 1) * CH;
                    for (int q8 = w; q8 < CH; q8 += 3) {
                        int t = base + q8;
                        int tc = t < T ? t : T - 1;
                        ex_lds[t & (NSLOT - 1)][l] =
                            __builtin_amdgcn_exp2f(xb[(size_t)tc * CC + l] * L2E);
                    }
                }
                WG_SYNC();
            }
        }
        return;
    }

    // ---------------- chain (wave 3) ----------------
    // A fragments: A[mt][ch] slot (g,i) = exp(trans[16mt+c][32ch + kappa(g,i)])
    bf16x8 A[4][2];
    #pragma unroll
    for (int mt = 0; mt < 4; ++mt) {
        const float* tr = trans + (16 * mt + c) * CC;
        #pragma unroll
        for (int ch = 0; ch < 2; ++ch) {
            float4 u = *(const float4*)(tr + 32 * ch + 4 * g);
            float4 v = *(const float4*)(tr + 32 * ch + 16 + 4 * g);
            PackAB pk;
            pk.w[0] = cvtpk(__builtin_amdgcn_exp2f(u.x * L2E), __builtin_amdgcn_exp2f(u.y * L2E));
            pk.w[1] = cvtpk(__builtin_amdgcn_exp2f(u.z * L2E), __builtin_amdgcn_exp2f(u.w * L2E));
            pk.w[2] = cvtpk(__builtin_amdgcn_exp2f(v.x * L2E), __builtin_amdgcn_exp2f(v.y * L2E));
            pk.w[3] = cvtpk(__builtin_amdgcn_exp2f(v.z * L2E), __builtin_amdgcn_exp2f(v.w * L2E));
            A[mt][ch] = pk.v;
        }
    }

    const int Lm1 = L - 1;
    float Mbar;
    float qv[4][4];
    {
        Mbar = (xb[0] + orig[0]) * L2E;
        #pragma unroll
        for (int mt = 0; mt < 4; ++mt) {
            f32x4 xv = *(const f32x4*)(xb + 16 * mt + 4 * g);
            f32x4 ov = *(const f32x4*)(orig + 16 * mt + 4 * g);
            #pragma unroll
            for (int r = 0; r < 4; ++r)
                qv[mt][r] = __builtin_amdgcn_exp2f((xv[r] + ov[r]) * L2E - Mbar);
        }
    }
    float qk[4][4]; float Mk = Mbar;
    #pragma unroll
    for (int mt = 0; mt < 4; ++mt)
        #pragma unroll
        for (int r = 0; r < 4; ++r) qk[mt][r] = qv[mt][r];

    PackAB B0, B1;
    #define BUILD_B() do {                                   \
        B0.w[0] = cvtpk(qv[0][0], qv[0][1]);                 \
        B0.w[1] = cvtpk(qv[0][2], qv[0][3]);                 \
        B0.w[2] = cvtpk(qv[1][0], qv[1][1]);                 \
        B0.w[3] = cvtpk(qv[1][2], qv[1][3]);                 \
        B1.w[0] = cvtpk(qv[2][0], qv[2][1]);                 \
        B1.w[1] = cvtpk(qv[2][2], qv[2][3]);                 \
        B1.w[2] = cvtpk(qv[3][0], qv[3][1]);                 \
        B1.w[3] = cvtpk(qv[3][2], qv[3][3]);                 \
    } while (0)
    BUILD_B();

    float prevS0 = 1.0f;   // r_1 = 1, log2 = 0

    #define LOADP(P, slot) do {                                           \
        const f32x4* ex4_ = (const f32x4*)&ex_lds[(slot)][0];             \
        P[0] = ex4_[g]; P[1] = ex4_[4 + g];                               \
        P[2] = ex4_[8 + g]; P[3] = ex4_[12 + g];                          \
    } while (0)

    #define STEP(tt, P, pfslot, doPF) do {                                \
        float r_   = __builtin_amdgcn_rcpf(prevS0);                       \
        float lgr_ = __builtin_amdgcn_logf(r_);                           \
        Mbar -= lgr_;                                                     \
        f32x4 exr0 = P[0] * r_, exr1 = P[1] * r_;                         \
        f32x4 exr2 = P[2] * r_, exr3 = P[3] * r_;                         \
        f32x4 Z = {0.f, 0.f, 0.f, 0.f};                                   \
        f32x4 d0 = __builtin_amdgcn_mfma_f32_16x16x32_bf16(A[0][0], B0.v, Z, 0, 0, 0); \
        f32x4 d1 = __builtin_amdgcn_mfma_f32_16x16x32_bf16(A[1][0], B0.v, Z, 0, 0, 0); \
        f32x4 d2 = __builtin_amdgcn_mfma_f32_16x16x32_bf16(A[2][0], B0.v, Z, 0, 0, 0); \
        f32x4 d3 = __builtin_amdgcn_mfma_f32_16x16x32_bf16(A[3][0], B0.v, Z, 0, 0, 0); \
        f32x4 e0 = __builtin_amdgcn_mfma_f32_16x16x32_bf16(A[0][1], B1.v, Z, 0, 0, 0); \
        f32x4 e1 = __builtin_amdgcn_mfma_f32_16x16x32_bf16(A[1][1], B1.v, Z, 0, 0, 0); \
        f32x4 e2 = __builtin_amdgcn_mfma_f32_16x16x32_bf16(A[2][1], B1.v, Z, 0, 0, 0); \
        f32x4 e3 = __builtin_amdgcn_mfma_f32_16x16x32_bf16(A[3][1], B1.v, Z, 0, 0, 0); \
        d0 += e0; d1 += e1; d2 += e2; d3 += e3;                           \
        prevS0 = bcast0(d0[0]);                                           \
        qv[0][0] = exr0[0] * d0[0]; qv[0][1] = exr0[1] * d0[1];           \
        qv[0][2] = exr0[2] * d0[2]; qv[0][3] = exr0[3] * d0[3];           \
        qv[1][0] = exr1[0] * d1[0]; qv[1][1] = exr1[1] * d1[1];           \
        qv[1][2] = exr1[2] * d1[2]; qv[1][3] = exr1[3] * d1[3];           \
        qv[2][0] = exr2[0] * d2[0]; qv[2][1] = exr2[1] * d2[1];           \
        qv[2][2] = exr2[2] * d2[2]; qv[2][3] = exr2[3] * d2[3];           \
        qv[3][0] = exr3[0] * d3[0]; qv[3][1] = exr3[1] * d3[1];           \
        qv[3][2] = exr3[2] * d3[2]; qv[3][3] = exr3[3] * d3[3];           \
        if ((tt) == Lm1) {                                                \
            for (int mt_ = 0; mt_ < 4; ++mt_)                             \
                for (int r2_ = 0; r2_ < 4; ++r2_) qk[mt_][r2_] = qv[mt_][r2_]; \
            Mk = Mbar;                                                    \
        }                                                                 \
        BUILD_B();                                                        \
        if (doPF) LOADP(P, pfslot);                                       \
    } while (0)

    if (nch > 0) {
        WG_SYNC();   // chunk 0 ready
        for (int cph = 0; cph < nch; ++cph) {
            int cbeg = (cph == 0) ? 1 : cph * CH;
            int cend = (cph + 1) * CH; if (cend > L) cend = L;
            int lastt = cend - 1;

            f32x4 P0[4], P1[4];
            LOADP(P0, cbeg & (NSLOT - 1));
            { int t1 = (cbeg + 1 <= lastt) ? cbeg + 1 : lastt;
              LOADP(P1, t1 & (NSLOT - 1)); }

            int t = cbeg;
            for (; t + 1 < cend; t += 2) {
                int pa = (t + 2 <= lastt) ? t + 2 : lastt;
                int pb = (t + 3 <= lastt) ? t + 3 : lastt;
                STEP(t,     P0, pa & (NSLOT - 1), 1);
                STEP(t + 1, P1, pb & (NSLOT - 1), 1);
            }
            if (t < cend) STEP(t, P0, 0, 0);

            WG_SYNC();   // phase done; producers may overwrite our chunk
        }
    }

    // epilogue: alpha = ln2*(Mk + log2 qk); out[b] = sum over 64 rows
    float s = 0.f;
    #pragma unroll
    for (int mt = 0; mt < 4; ++mt)
        #pragma unroll
        for (int r = 0; r < 4; ++r)
            s += LN2 * (Mk + __builtin_amdgcn_logf(qk[mt][r]));
    s = pairsum16(s);      // + g^1 partner
    s = pairsum32(s, l);   // + g^2 partner -> sum over 4 g-groups
    if (l == 0) out[b] = s;
}

extern "C" void kernel_launch(void* const* d_in, const int* in_sizes, int n_in,
                              void* d_out, int out_size, void* d_ws, size_t ws_size,
                              hipStream_t stream) {
    const float* x     = (const float*)d_in[0];
    const float* trans = (const float*)d_in[1];
    const float* orig  = (const float*)d_in[2];
    const int*   lens  = (const int*)d_in[3];
    float* out = (float*)d_out;

    const int B = in_sizes[3];
    const int T = in_sizes[0] / (B * CC);

    crf_fwd_kernel<<<B, 256, 0, stream>>>(x, trans, orig, lens, out, T);
}

// Round 8
// 361.804 us; speedup vs baseline: 1.5555x; 1.5555x over previous
//
#include <hip/hip_runtime.h>

// CRF forward via parallel-in-time segmented scan.  B=256, T<=2048, C=64.
// q_t = diag(ex_t)·E·q_{t-1}  (linear!)  =>  split t into P segments:
// K1: one block per (batch,segment): M_s = prod_{t in seg} diag(ex_t)·E,
//     computed as 256-ish serial 64x64x64 matmuls on ONE chain wave:
//     32x mfma_f32_16x16x32_bf16 per step, with the (verified, rounds 6/7)
//     kappa(g,i)=4g+(i&3)+16(i>>2) bijection on BOTH A(=exp(trans)) and B so
//     the D tile each lane holds is exactly its next B-fragment -> lane-local
//     recirculation (32 cvt_pk). Renorm r=rcp(prev D[0][0]), Lseg-=log2(r)
//     (exact bookkeeping). 3 producer waves stream ex=2^(x*log2e) into a
//     double-buffered LDS chunk ring (CH=32). Raw s_barrier (no vmcnt drain).
// K2: one wave per batch: q <- renorm(M_s·q) over segments (VALU matvec from
//     LDS), Mbar accumulates all scales exactly; out = sum ln2*(Mbar+log2 q).

#define CC 64
#define CH 32
#define NSLOT 64   // 2*CH double buffer

typedef short bf16x8 __attribute__((ext_vector_type(8)));
typedef float f32x4 __attribute__((ext_vector_type(4)));

union PackAB { int w[4]; bf16x8 v; };

__device__ __forceinline__ int cvtpk(float lo, float hi) {
    int r;
    asm("v_cvt_pk_bf16_f32 %0, %1, %2" : "=v"(r) : "v"(lo), "v"(hi));
    return r;
}
__device__ __forceinline__ float bcast0(float v) {
    return __int_as_float(__builtin_amdgcn_readfirstlane(__float_as_int(v)));
}

#define WG_SYNC() do {                                      \
    asm volatile("s_waitcnt lgkmcnt(0)" ::: "memory");      \
    __builtin_amdgcn_s_barrier();                           \
    asm volatile("" ::: "memory");                          \
} while (0)

#define LDS_FENCE() asm volatile("s_waitcnt lgkmcnt(0)" ::: "memory")

// one matmul step: M_new = diag(exr rows)·(E·M_old), M_old lives in Bf, M_new -> V, Bf
__device__ __forceinline__ void chain_step(const bf16x8 (&A)[4][2], PackAB (&Bf)[2][4],
                                           f32x4 (&V)[4][4], const f32x4 (&PP)[4],
                                           float& prevS0, float& Lseg) {
    float r_   = __builtin_amdgcn_rcpf(prevS0);
    float lgr_ = __builtin_amdgcn_logf(r_);      // log2 of ACTUAL scale applied
    Lseg -= lgr_;
    f32x4 exr[4];
    #pragma unroll
    for (int mt = 0; mt < 4; ++mt) exr[mt] = PP[mt] * r_;
    f32x4 Zz = {0.f, 0.f, 0.f, 0.f};
    f32x4 Dk[4][4];
    #pragma unroll
    for (int mt = 0; mt < 4; ++mt)
        #pragma unroll
        for (int nt = 0; nt < 4; ++nt) {
            f32x4 t0 = __builtin_amdgcn_mfma_f32_16x16x32_bf16(A[mt][0], Bf[0][nt].v, Zz, 0, 0, 0);
            Dk[mt][nt] = __builtin_amdgcn_mfma_f32_16x16x32_bf16(A[mt][1], Bf[1][nt].v, t0, 0, 0, 0);
        }
    prevS0 = bcast0(Dk[0][0][0]);   // lane 0 = row 0, col 0 (verified D layout)
    #pragma unroll
    for (int mt = 0; mt < 4; ++mt)
        #pragma unroll
        for (int nt = 0; nt < 4; ++nt) V[mt][nt] = exr[mt] * Dk[mt][nt];
    #pragma unroll
    for (int nt = 0; nt < 4; ++nt) {
        Bf[0][nt].w[0] = cvtpk(V[0][nt][0], V[0][nt][1]);
        Bf[0][nt].w[1] = cvtpk(V[0][nt][2], V[0][nt][3]);
        Bf[0][nt].w[2] = cvtpk(V[1][nt][0], V[1][nt][1]);
        Bf[0][nt].w[3] = cvtpk(V[1][nt][2], V[1][nt][3]);
        Bf[1][nt].w[0] = cvtpk(V[2][nt][0], V[2][nt][1]);
        Bf[1][nt].w[1] = cvtpk(V[2][nt][2], V[2][nt][3]);
        Bf[1][nt].w[2] = cvtpk(V[3][nt][0], V[3][nt][1]);
        Bf[1][nt].w[3] = cvtpk(V[3][nt][2], V[3][nt][3]);
    }
}

__launch_bounds__(256, 2)
__global__ void crf_seg_kernel(const float* __restrict__ x,      // (B,T,C)
                               const float* __restrict__ trans,  // (C,C)
                               const int*   __restrict__ lens,   // (B,)
                               float* __restrict__ Mws,          // (B*P,64,64)
                               float* __restrict__ Ls,           // (B*P,)
                               int T, int Pseg, int Pshift, int SEG) {
    const int blk = blockIdx.x;
    const int b = blk >> Pshift;
    const int s = blk & (Pseg - 1);
    const int L = lens[b];
    const int tbeg = s * SEG;
    int segend = (s + 1) * SEG; if (segend > L - 1) segend = L - 1;
    const int nsteps = segend - tbeg;           // steps t = tbeg+1 .. segend
    if (nsteps <= 0) return;                    // inactive block (all waves exit)

    const int tid = threadIdx.x, w = tid >> 6, l = tid & 63;
    const int c = l & 15, g = l >> 4;
    const float L2E = 1.4426950408889634f;
    __shared__ float ex_lds[NSLOT][CC];         // 16 KiB
    const float* xb = x + (size_t)b * T * CC;
    const int nch = (nsteps + CH - 1) / CH;

    if (w < 3) {
        // ---------------- producers ----------------
        int c0end = nsteps < CH ? nsteps : CH;
        for (int idx = w; idx < c0end; idx += 3)
            ex_lds[idx & (NSLOT - 1)][l] =
                __builtin_amdgcn_exp2f(xb[(size_t)(tbeg + 1 + idx) * CC + l] * L2E);
        WG_SYNC();
        for (int cph = 0; cph < nch; ++cph) {
            if (cph + 1 < nch) {
                int beg = (cph + 1) * CH, e2 = beg + CH; if (e2 > nsteps) e2 = nsteps;
                for (int idx = beg + w; idx < e2; idx += 3)
                    ex_lds[idx & (NSLOT - 1)][l] =
                        __builtin_amdgcn_exp2f(xb[(size_t)(tbeg + 1 + idx) * CC + l] * L2E);
            }
            WG_SYNC();
        }
        return;
    }

    // ---------------- chain (wave 3) ----------------
    // A frags: A[mt][ch] slot (g,i) = exp(trans[16mt+c][32ch + kappa(g,i)])
    bf16x8 A[4][2];
    #pragma unroll
    for (int mt = 0; mt < 4; ++mt) {
        const float* tr = trans + (16 * mt + c) * CC;
        #pragma unroll
        for (int ch = 0; ch < 2; ++ch) {
            float4 u = *(const float4*)(tr + 32 * ch + 4 * g);
            float4 v = *(const float4*)(tr + 32 * ch + 16 + 4 * g);
            PackAB pk;
            pk.w[0] = cvtpk(__builtin_amdgcn_exp2f(u.x * L2E), __builtin_amdgcn_exp2f(u.y * L2E));
            pk.w[1] = cvtpk(__builtin_amdgcn_exp2f(u.z * L2E), __builtin_amdgcn_exp2f(u.w * L2E));
            pk.w[2] = cvtpk(__builtin_amdgcn_exp2f(v.x * L2E), __builtin_amdgcn_exp2f(v.y * L2E));
            pk.w[3] = cvtpk(__builtin_amdgcn_exp2f(v.z * L2E), __builtin_amdgcn_exp2f(v.w * L2E));
            A[mt][ch] = pk.v;
        }
    }
    // B frags = identity: B[k][col] = (k==col), k = 32ch + kappa(g,i), col = 16nt+c
    PackAB Bf[2][4];
    #pragma unroll
    for (int ch = 0; ch < 2; ++ch)
        #pragma unroll
        for (int nt = 0; nt < 4; ++nt)
            #pragma unroll
            for (int qq = 0; qq < 4; ++qq) {
                int i0 = 2 * qq, i1 = 2 * qq + 1;
                int k0 = 32 * ch + 4 * g + (i0 & 3) + 16 * (i0 >> 2);
                int k1 = 32 * ch + 4 * g + (i1 & 3) + 16 * (i1 >> 2);
                Bf[ch][nt].w[qq] = cvtpk((k0 == 16 * nt + c) ? 1.f : 0.f,
                                         (k1 == 16 * nt + c) ? 1.f : 0.f);
            }

    #define LOADP(PP, slot) do {                                          \
        const f32x4* e4_ = (const f32x4*)&ex_lds[(slot)][0];              \
        PP[0] = e4_[g]; PP[1] = e4_[4 + g];                               \
        PP[2] = e4_[8 + g]; PP[3] = e4_[12 + g];                          \
    } while (0)

    float Lseg = 0.f, prevS0 = 1.0f;   // first step: r=1, log2=0
    f32x4 V[4][4];

    WG_SYNC();   // chunk 0 ready
    int idx = 0;
    for (int cph = 0; cph < nch; ++cph) {
        int cend = (cph + 1) * CH; if (cend > nsteps) cend = nsteps;
        int lastidx = cend - 1;
        f32x4 Pa[4], Pb[4];
        LOADP(Pa, idx & (NSLOT - 1));
        { int i1 = (idx + 1 <= lastidx) ? idx + 1 : lastidx;
          LOADP(Pb, i1 & (NSLOT - 1)); }
        for (; idx + 1 < cend; idx += 2) {
            chain_step(A, Bf, V, Pa, prevS0, Lseg);
            { int pa = (idx + 2 <= lastidx) ? idx + 2 : lastidx;
              LOADP(Pa, pa & (NSLOT - 1)); }
            chain_step(A, Bf, V, Pb, prevS0, Lseg);
            { int pb = (idx + 3 <= lastidx) ? idx + 3 : lastidx;
              LOADP(Pb, pb & (NSLOT - 1)); }
        }
        if (idx < cend) { chain_step(A, Bf, V, Pa, prevS0, Lseg); ++idx; }
        WG_SYNC();   // producers may overwrite our chunk
    }

    // store M_s (f32, canonical [row][col]) + Lseg
    float* Mo = Mws + (size_t)blk * 4096;
    #pragma unroll
    for (int mt = 0; mt < 4; ++mt)
        #pragma unroll
        for (int nt = 0; nt < 4; ++nt)
            #pragma unroll
            for (int rr = 0; rr < 4; ++rr)
                Mo[(16 * mt + 4 * g + rr) * 64 + 16 * nt + c] = V[mt][nt][rr];
    if (l == 0) Ls[blk] = Lseg;
    #undef LOADP
}

__launch_bounds__(64, 1)
__global__ void crf_apply_kernel(const float* __restrict__ x,
                                 const float* __restrict__ orig,
                                 const int*   __restrict__ lens,
                                 const float* __restrict__ Mws,
                                 const float* __restrict__ Ls,
                                 float* __restrict__ out,
                                 int T, int Pseg, int SEG) {
    const int b = blockIdx.x, j = threadIdx.x;
    __shared__ float Ml[64 * 68];   // +4 pad per row: fewer bank conflicts
    __shared__ float qb[CC];
    const float L2E = 1.4426950408889634f, LN2 = 0.6931471805599453f;
    const int L = lens[b];
    const float* xb = x + (size_t)b * T * CC;

    float Mbar = (xb[0] + orig[0]) * L2E;
    float q = __builtin_amdgcn_exp2f((xb[j] + orig[j]) * L2E - Mbar);

    for (int s = 0; s < Pseg; ++s) {
        int tbeg = s * SEG;
        int segend = (s + 1) * SEG; if (segend > L - 1) segend = L - 1;
        if (segend - tbeg <= 0) break;   // lens sorted per batch; later segs inactive too
        const float* Ms = Mws + ((size_t)b * Pseg + s) * 4096;
        #pragma unroll
        for (int i = 0; i < 16; ++i) {   // coalesced stage: 16x b128 per lane
            f32x4 v = *(const f32x4*)(Ms + i * 256 + j * 4);
            int row = i * 4 + (j >> 4);
            int col = (j & 15) * 4;
            *(f32x4*)&Ml[row * 68 + col] = v;
        }
        qb[j] = q;
        LDS_FENCE();   // single wave: write->read ordering
        float a0 = 0.f, a1 = 0.f, a2 = 0.f, a3 = 0.f;
        #pragma unroll
        for (int k4 = 0; k4 < 16; ++k4) {
            f32x4 m  = *(const f32x4*)&Ml[j * 68 + k4 * 4];
            f32x4 qv = *(const f32x4*)&qb[k4 * 4];
            a0 = fmaf(m[0], qv[0], a0); a1 = fmaf(m[1], qv[1], a1);
            a2 = fmaf(m[2], qv[2], a2); a3 = fmaf(m[3], qv[3], a3);
        }
        float S = (a0 + a1) + (a2 + a3);
        Mbar += Ls[(size_t)b * Pseg + s];
        float p = bcast0(S);
        float r = __builtin_amdgcn_rcpf(p);
        float lgr = __builtin_amdgcn_logf(r);
        q = S * r;
        Mbar -= lgr;
        LDS_FENCE();   // reads done before next stage overwrites
    }

    float alpha = LN2 * (Mbar + __builtin_amdgcn_logf(q));
    alpha += __shfl_xor(alpha, 1, 64);
    alpha += __shfl_xor(alpha, 2, 64);
    alpha += __shfl_xor(alpha, 4, 64);
    alpha += __shfl_xor(alpha, 8, 64);
    alpha += __shfl_xor(alpha, 16, 64);
    alpha += __shfl_xor(alpha, 32, 64);
    if (j == 0) out[b] = alpha;
}

extern "C" void kernel_launch(void* const* d_in, const int* in_sizes, int n_in,
                              void* d_out, int out_size, void* d_ws, size_t ws_size,
                              hipStream_t stream) {
    const float* x     = (const float*)d_in[0];
    const float* trans = (const float*)d_in[1];
    const float* orig  = (const float*)d_in[2];
    const int*   lens  = (const int*)d_in[3];
    float* out = (float*)d_out;

    const int B = in_sizes[3];
    const int T = in_sizes[0] / (B * CC);

    int P = 8, Pshift = 3;
    while (P > 1 && ws_size < (size_t)B * P * (4096 * 4 + 4)) { P >>= 1; --Pshift; }
    const int SEG = (T + P - 1) / P;

    float* Mws = (float*)d_ws;
    float* Ls  = Mws + (size_t)B * P * 4096;

    crf_seg_kernel<<<B * P, 256, 0, stream>>>(x, trans, lens, Mws, Ls, T, P, Pshift, SEG);
    crf_apply_kernel<<<B, 64, 0, stream>>>(x, orig, lens, Mws, Ls, out, T, P, SEG);
}

// Round 10
// 252.581 us; speedup vs baseline: 2.2281x; 1.4324x over previous
//
#include <hip/hip_runtime.h>

// CRF forward via parallel-in-time segmented scan. B=256, T<=2048, C=64.
// q_t = diag(ex_t)·E·q_{t-1} (linear) => P=16 segments per batch.
// K1: ONE 64-thread block per (batch,segment) — zero LDS, zero barriers.
//     Chain = round-8's proven single-wave 64x64 matmul step verbatim:
//     32x mfma_f32_16x16x32_bf16 per step; kappa(g,i)=4g+(i&3)+16(i>>2)
//     bijection on BOTH A(=exp(trans)) and B (verified rounds 6-8) makes the
//     D tile each lane holds exactly its next B-fragment -> lane-local
//     recirculation via cvt_pk. Renorm r=rcp(prev raw D[0][0]),
//     Lseg -= log2(r) (exact bookkeeping). Self-feeding: 2-deep named
//     register x ring + inline exp2 (no producers -> 8 chain waves/CU).
// K2: one wave per batch applies q <- renorm(M_s·q) over segments (proven).

#define CC 64

typedef short bf16x8 __attribute__((ext_vector_type(8)));
typedef float f32x4 __attribute__((ext_vector_type(4)));

union PackAB { int w[4]; bf16x8 v; };

__device__ __forceinline__ int cvtpk(float lo, float hi) {
    int r;
    asm("v_cvt_pk_bf16_f32 %0, %1, %2" : "=v"(r) : "v"(lo), "v"(hi));
    return r;
}
__device__ __forceinline__ float bcast0(float v) {
    return __int_as_float(__builtin_amdgcn_readfirstlane(__float_as_int(v)));
}

#define LDS_FENCE() asm volatile("s_waitcnt lgkmcnt(0)" ::: "memory")

// one matmul step: M_new = diag(exp2(x*L2E)*r)·(E·M_old); M lives in Bf (bf16)
__device__ __forceinline__ void chain_step(const bf16x8 (&A)[4][2], PackAB (&Bf)[2][4],
                                           f32x4 (&XP)[4],
                                           const float* __restrict__ xb,
                                           int tbeg, int segend, int idx, int g,
                                           float& prevS0, float& Lseg) {
    const float L2E = 1.4426950408889634f;
    float r_   = __builtin_amdgcn_rcpf(prevS0);
    float lgr_ = __builtin_amdgcn_logf(r_);      // log2 of ACTUAL scale applied
    Lseg -= lgr_;

    f32x4 exr[4];
    #pragma unroll
    for (int mt = 0; mt < 4; ++mt) {
        f32x4 xv = XP[mt];
        #pragma unroll
        for (int r = 0; r < 4; ++r)
            exr[mt][r] = __builtin_amdgcn_exp2f(xv[r] * L2E) * r_;
    }
    // refill this ring slot for step idx+2
    {
        int tp = tbeg + 3 + idx; if (tp > segend) tp = segend;
        const float* xp = xb + (size_t)tp * CC + 4 * g;
        #pragma unroll
        for (int mt = 0; mt < 4; ++mt)
            XP[mt] = *(const f32x4*)(xp + 16 * mt);
    }

    float ns0 = 0.f;
    #pragma unroll
    for (int nt = 0; nt < 4; ++nt) {   // per-nt: D uses only Bf[*][nt] -> safe overwrite
        f32x4 Z = {0.f, 0.f, 0.f, 0.f};
        f32x4 t0, d0, d1, d2, d3;
        t0 = __builtin_amdgcn_mfma_f32_16x16x32_bf16(A[0][0], Bf[0][nt].v, Z, 0, 0, 0);
        d0 = __builtin_amdgcn_mfma_f32_16x16x32_bf16(A[0][1], Bf[1][nt].v, t0, 0, 0, 0);
        t0 = __builtin_amdgcn_mfma_f32_16x16x32_bf16(A[1][0], Bf[0][nt].v, Z, 0, 0, 0);
        d1 = __builtin_amdgcn_mfma_f32_16x16x32_bf16(A[1][1], Bf[1][nt].v, t0, 0, 0, 0);
        t0 = __builtin_amdgcn_mfma_f32_16x16x32_bf16(A[2][0], Bf[0][nt].v, Z, 0, 0, 0);
        d2 = __builtin_amdgcn_mfma_f32_16x16x32_bf16(A[2][1], Bf[1][nt].v, t0, 0, 0, 0);
        t0 = __builtin_amdgcn_mfma_f32_16x16x32_bf16(A[3][0], Bf[0][nt].v, Z, 0, 0, 0);
        d3 = __builtin_amdgcn_mfma_f32_16x16x32_bf16(A[3][1], Bf[1][nt].v, t0, 0, 0, 0);
        if (nt == 0) ns0 = d0[0];                 // raw D[0][0], pre-scale
        d0 *= exr[0]; d1 *= exr[1]; d2 *= exr[2]; d3 *= exr[3];
        Bf[0][nt].w[0] = cvtpk(d0[0], d0[1]);
        Bf[0][nt].w[1] = cvtpk(d0[2], d0[3]);
        Bf[0][nt].w[2] = cvtpk(d1[0], d1[1]);
        Bf[0][nt].w[3] = cvtpk(d1[2], d1[3]);
        Bf[1][nt].w[0] = cvtpk(d2[0], d2[1]);
        Bf[1][nt].w[1] = cvtpk(d2[2], d2[3]);
        Bf[1][nt].w[2] = cvtpk(d3[0], d3[1]);
        Bf[1][nt].w[3] = cvtpk(d3[2], d3[3]);
    }
    prevS0 = bcast0(ns0);   // lane 0 = (row 0, col 0), verified D layout
}

__launch_bounds__(64, 2)
__global__ void crf_seg_kernel(const float* __restrict__ x,      // (B,T,C)
                               const float* __restrict__ trans,  // (C,C)
                               const int*   __restrict__ lens,   // (B,)
                               float* __restrict__ Mws,          // (B*P,64,64)
                               float* __restrict__ Ls,           // (B*P,)
                               int T, int Pseg, int Pshift, int SEG) {
    const int blk = blockIdx.x;
    const int b = blk >> Pshift;
    const int s = blk & (Pseg - 1);
    const int L = lens[b];
    const int tbeg = s * SEG;
    int segend = (s + 1) * SEG; if (segend > L - 1) segend = L - 1;
    const int nsteps = segend - tbeg;      // matmul steps t = tbeg+1 .. segend
    if (nsteps <= 0) return;

    const int l = threadIdx.x;
    const int c = l & 15, g = l >> 4;
    const float L2E = 1.4426950408889634f;
    const float* xb = x + (size_t)b * T * CC;

    // A frags: A[mt][ch] slot (g,i) = exp(trans[16mt+c][32ch + kappa(g,i)])
    bf16x8 A[4][2];
    #pragma unroll
    for (int mt = 0; mt < 4; ++mt) {
        const float* tr = trans + (16 * mt + c) * CC;
        #pragma unroll
        for (int ch = 0; ch < 2; ++ch) {
            float4 u = *(const float4*)(tr + 32 * ch + 4 * g);
            float4 v = *(const float4*)(tr + 32 * ch + 16 + 4 * g);
            PackAB pk;
            pk.w[0] = cvtpk(__builtin_amdgcn_exp2f(u.x * L2E), __builtin_amdgcn_exp2f(u.y * L2E));
            pk.w[1] = cvtpk(__builtin_amdgcn_exp2f(u.z * L2E), __builtin_amdgcn_exp2f(u.w * L2E));
            pk.w[2] = cvtpk(__builtin_amdgcn_exp2f(v.x * L2E), __builtin_amdgcn_exp2f(v.y * L2E));
            pk.w[3] = cvtpk(__builtin_amdgcn_exp2f(v.z * L2E), __builtin_amdgcn_exp2f(v.w * L2E));
            A[mt][ch] = pk.v;
        }
    }
    // B = identity in fragment form (round-8 verbatim)
    PackAB Bf[2][4];
    #pragma unroll
    for (int ch = 0; ch < 2; ++ch)
        #pragma unroll
        for (int nt = 0; nt < 4; ++nt)
            #pragma unroll
            for (int qq = 0; qq < 4; ++qq) {
                int i0 = 2 * qq, i1 = 2 * qq + 1;
                int k0 = 32 * ch + 4 * g + (i0 & 3) + 16 * (i0 >> 2);
                int k1 = 32 * ch + 4 * g + (i1 & 3) + 16 * (i1 >> 2);
                Bf[ch][nt].w[qq] = cvtpk((k0 == 16 * nt + c) ? 1.f : 0.f,
                                         (k1 == 16 * nt + c) ? 1.f : 0.f);
            }

    // 2-deep named x prefetch ring (static indexing only)
    f32x4 XPa[4], XPb[4];
    {
        int t0_ = tbeg + 1;
        int t1_ = tbeg + 2; if (t1_ > segend) t1_ = segend;
        const float* xp0 = xb + (size_t)t0_ * CC + 4 * g;
        const float* xp1 = xb + (size_t)t1_ * CC + 4 * g;
        #pragma unroll
        for (int mt = 0; mt < 4; ++mt) {
            XPa[mt] = *(const f32x4*)(xp0 + 16 * mt);
            XPb[mt] = *(const f32x4*)(xp1 + 16 * mt);
        }
    }

    float Lseg = 0.f, prevS0 = 1.0f;   // first step: r=1, log2=0
    int idx = 0;
    while (true) {
        chain_step(A, Bf, XPa, xb, tbeg, segend, idx, g, prevS0, Lseg);
        if (++idx >= nsteps) break;
        chain_step(A, Bf, XPb, xb, tbeg, segend, idx, g, prevS0, Lseg);
        if (++idx >= nsteps) break;
    }

    // store M_s canonical [row][col] f32 (unpack bf16 Bf) + Lseg
    float* Mo = Mws + (size_t)blk * 4096;
    #pragma unroll
    for (int ch = 0; ch < 2; ++ch)
        #pragma unroll
        for (int nt = 0; nt < 4; ++nt)
            #pragma unroll
            for (int e = 0; e < 8; ++e) {
                unsigned wb = (unsigned)Bf[ch][nt].w[e >> 1];
                unsigned hb = (e & 1) ? (wb >> 16) : (wb & 0xffffu);
                int row = 32 * ch + 4 * g + (e & 3) + 16 * (e >> 2);
                Mo[row * 64 + 16 * nt + c] = __uint_as_float(hb << 16);
            }
    if (l == 0) Ls[blk] = Lseg;
}

__launch_bounds__(64, 1)
__global__ void crf_apply_kernel(const float* __restrict__ x,
                                 const float* __restrict__ orig,
                                 const int*   __restrict__ lens,
                                 const float* __restrict__ Mws,
                                 const float* __restrict__ Ls,
                                 float* __restrict__ out,
                                 int T, int Pseg, int SEG) {
    const int b = blockIdx.x, j = threadIdx.x;
    __shared__ float Ml[64 * 68];   // +4 pad per row
    __shared__ float qb[CC];
    const float L2E = 1.4426950408889634f, LN2 = 0.6931471805599453f;
    const int L = lens[b];
    const float* xb = x + (size_t)b * T * CC;

    float Mbar = (xb[0] + orig[0]) * L2E;
    float q = __builtin_amdgcn_exp2f((xb[j] + orig[j]) * L2E - Mbar);

    for (int s = 0; s < Pseg; ++s) {
        int tbeg = s * SEG;
        int segend = (s + 1) * SEG; if (segend > L - 1) segend = L - 1;
        if (segend - tbeg <= 0) break;   // later segments inactive too
        const float* Ms = Mws + ((size_t)b * Pseg + s) * 4096;
        #pragma unroll
        for (int i = 0; i < 16; ++i) {   // coalesced stage: 16x b128 per lane
            f32x4 v = *(const f32x4*)(Ms + i * 256 + j * 4);
            int row = i * 4 + (j >> 4);
            int col = (j & 15) * 4;
            *(f32x4*)&Ml[row * 68 + col] = v;
        }
        qb[j] = q;
        LDS_FENCE();
        float a0 = 0.f, a1 = 0.f, a2 = 0.f, a3 = 0.f;
        #pragma unroll
        for (int k4 = 0; k4 < 16; ++k4) {
            f32x4 m  = *(const f32x4*)&Ml[j * 68 + k4 * 4];
            f32x4 qv = *(const f32x4*)&qb[k4 * 4];
            a0 = fmaf(m[0], qv[0], a0); a1 = fmaf(m[1], qv[1], a1);
            a2 = fmaf(m[2], qv[2], a2); a3 = fmaf(m[3], qv[3], a3);
        }
        float S = (a0 + a1) + (a2 + a3);
        Mbar += Ls[(size_t)b * Pseg + s];
        float p = bcast0(S);
        float r = __builtin_amdgcn_rcpf(p);
        float lgr = __builtin_amdgcn_logf(r);
        q = S * r;
        Mbar -= lgr;
        LDS_FENCE();
    }

    float alpha = LN2 * (Mbar + __builtin_amdgcn_logf(q));
    alpha += __shfl_xor(alpha, 1, 64);
    alpha += __shfl_xor(alpha, 2, 64);
    alpha += __shfl_xor(alpha, 4, 64);
    alpha += __shfl_xor(alpha, 8, 64);
    alpha += __shfl_xor(alpha, 16, 64);
    alpha += __shfl_xor(alpha, 32, 64);
    if (j == 0) out[b] = alpha;
}

extern "C" void kernel_launch(void* const* d_in, const int* in_sizes, int n_in,
                              void* d_out, int out_size, void* d_ws, size_t ws_size,
                              hipStream_t stream) {
    const float* x     = (const float*)d_in[0];
    const float* trans = (const float*)d_in[1];
    const float* orig  = (const float*)d_in[2];
    const int*   lens  = (const int*)d_in[3];
    float* out = (float*)d_out;

    const int B = in_sizes[3];
    const int T = in_sizes[0] / (B * CC);

    int P = 16, Pshift = 4;
    while (P > 1 && ws_size < (size_t)B * P * (4096 * 4 + 4)) { P >>= 1; --Pshift; }
    const int SEG = (T + P - 1) / P;

    float* Mws = (float*)d_ws;
    float* Ls  = Mws + (size_t)B * P * 4096;

    crf_seg_kernel<<<B * P, 64, 0, stream>>>(x, trans, lens, Mws, Ls, T, P, Pshift, SEG);
    crf_apply_kernel<<<B, 64, 0, stream>>>(x, orig, lens, Mws, Ls, out, T, P, SEG);
}

// Round 11
// 211.451 us; speedup vs baseline: 2.6615x; 1.1945x over previous
//
#include <hip/hip_runtime.h>

// CRF forward via parallel-in-time segmented scan. B=256, T<=2048, C=64.
// q_t = diag(ex_t)·E·q_{t-1} (linear) => P=64 segments per batch (SEG=32).
// K1: ONE 64-thread block per (batch,segment) — zero LDS, zero barriers.
//     Proven round-10 chain: 32x mfma_f32_16x16x32_bf16 per step;
//     kappa(g,i)=4g+(i&3)+16(i>>2) on BOTH A(=exp(trans)) and B makes the
//     D tile each lane holds exactly its next B-fragment (lane-local
//     recirculation via cvt_pk). Renorm folded into exp2 arg:
//     exr = 2^(x*L2E + lgr), lgr = log2(rcp(prev raw D[0][0]));
//     Lseg -= lgr => applied scale == bookkeeping exactly.
//     M_s stored as bf16 row-major (M is bf16-rounded每step anyway).
// K2: one wave per batch: q <- renorm(M_s·q) over segments; lane j owns row j,
//     loads its bf16 row (8x uint4, 1-deep prefetch), unpack = shift<<16.

#define CC 64

typedef short bf16x8 __attribute__((ext_vector_type(8)));
typedef float f32x4 __attribute__((ext_vector_type(4)));

union PackAB { int w[4]; bf16x8 v; };

__device__ __forceinline__ int cvtpk(float lo, float hi) {
    int r;
    asm("v_cvt_pk_bf16_f32 %0, %1, %2" : "=v"(r) : "v"(lo), "v"(hi));
    return r;
}
__device__ __forceinline__ float bcast0(float v) {
    return __int_as_float(__builtin_amdgcn_readfirstlane(__float_as_int(v)));
}

#define LDS_FENCE() asm volatile("s_waitcnt lgkmcnt(0)" ::: "memory")

// one matmul step: M_new = diag(2^(x*L2E+lgr))·(E·M_old); M lives in Bf (bf16)
__device__ __forceinline__ void chain_step(const bf16x8 (&A)[4][2], PackAB (&Bf)[2][4],
                                           f32x4 (&XP)[4],
                                           const float* __restrict__ xb,
                                           int tbeg, int segend, int idx, int g,
                                           float& prevS0, float& Lseg) {
    const float L2E = 1.4426950408889634f;
    float r_   = __builtin_amdgcn_rcpf(prevS0);
    float lgr_ = __builtin_amdgcn_logf(r_);      // log2 of scale; applied via exp2 arg
    Lseg -= lgr_;

    f32x4 exr[4];
    #pragma unroll
    for (int mt = 0; mt < 4; ++mt) {
        f32x4 xv = XP[mt];
        #pragma unroll
        for (int r = 0; r < 4; ++r)
            exr[mt][r] = __builtin_amdgcn_exp2f(fmaf(xv[r], L2E, lgr_));
    }
    // refill this ring slot for step idx+2
    {
        int tp = tbeg + 3 + idx; if (tp > segend) tp = segend;
        const float* xp = xb + (size_t)tp * CC + 4 * g;
        #pragma unroll
        for (int mt = 0; mt < 4; ++mt)
            XP[mt] = *(const f32x4*)(xp + 16 * mt);
    }

    float ns0 = 0.f;
    #pragma unroll
    for (int nt = 0; nt < 4; ++nt) {   // per-nt: D uses only Bf[*][nt] -> safe overwrite
        f32x4 Z = {0.f, 0.f, 0.f, 0.f};
        f32x4 t0, d0, d1, d2, d3;
        t0 = __builtin_amdgcn_mfma_f32_16x16x32_bf16(A[0][0], Bf[0][nt].v, Z, 0, 0, 0);
        d0 = __builtin_amdgcn_mfma_f32_16x16x32_bf16(A[0][1], Bf[1][nt].v, t0, 0, 0, 0);
        t0 = __builtin_amdgcn_mfma_f32_16x16x32_bf16(A[1][0], Bf[0][nt].v, Z, 0, 0, 0);
        d1 = __builtin_amdgcn_mfma_f32_16x16x32_bf16(A[1][1], Bf[1][nt].v, t0, 0, 0, 0);
        t0 = __builtin_amdgcn_mfma_f32_16x16x32_bf16(A[2][0], Bf[0][nt].v, Z, 0, 0, 0);
        d2 = __builtin_amdgcn_mfma_f32_16x16x32_bf16(A[2][1], Bf[1][nt].v, t0, 0, 0, 0);
        t0 = __builtin_amdgcn_mfma_f32_16x16x32_bf16(A[3][0], Bf[0][nt].v, Z, 0, 0, 0);
        d3 = __builtin_amdgcn_mfma_f32_16x16x32_bf16(A[3][1], Bf[1][nt].v, t0, 0, 0, 0);
        if (nt == 0) ns0 = d0[0];                 // raw D[0][0], pre-scale
        d0 *= exr[0]; d1 *= exr[1]; d2 *= exr[2]; d3 *= exr[3];
        Bf[0][nt].w[0] = cvtpk(d0[0], d0[1]);
        Bf[0][nt].w[1] = cvtpk(d0[2], d0[3]);
        Bf[0][nt].w[2] = cvtpk(d1[0], d1[1]);
        Bf[0][nt].w[3] = cvtpk(d1[2], d1[3]);
        Bf[1][nt].w[0] = cvtpk(d2[0], d2[1]);
        Bf[1][nt].w[1] = cvtpk(d2[2], d2[3]);
        Bf[1][nt].w[2] = cvtpk(d3[0], d3[1]);
        Bf[1][nt].w[3] = cvtpk(d3[2], d3[3]);
    }
    prevS0 = bcast0(ns0);   // lane 0 = (row 0, col 0), verified D layout
}

__launch_bounds__(64, 2)
__global__ void crf_seg_kernel(const float* __restrict__ x,      // (B,T,C)
                               const float* __restrict__ trans,  // (C,C)
                               const int*   __restrict__ lens,   // (B,)
                               unsigned short* __restrict__ Mws, // (B*P,64,64) bf16
                               float* __restrict__ Ls,           // (B*P,)
                               int T, int Pseg, int Pshift, int SEG) {
    const int blk = blockIdx.x;
    const int b = blk >> Pshift;
    const int s = blk & (Pseg - 1);
    const int L = lens[b];
    const int tbeg = s * SEG;
    int segend = (s + 1) * SEG; if (segend > L - 1) segend = L - 1;
    const int nsteps = segend - tbeg;      // matmul steps t = tbeg+1 .. segend
    if (nsteps <= 0) return;

    const int l = threadIdx.x;
    const int c = l & 15, g = l >> 4;
    const float L2E = 1.4426950408889634f;
    const float* xb = x + (size_t)b * T * CC;

    // A frags: A[mt][ch] slot (g,i) = exp(trans[16mt+c][32ch + kappa(g,i)])
    bf16x8 A[4][2];
    #pragma unroll
    for (int mt = 0; mt < 4; ++mt) {
        const float* tr = trans + (16 * mt + c) * CC;
        #pragma unroll
        for (int ch = 0; ch < 2; ++ch) {
            float4 u = *(const float4*)(tr + 32 * ch + 4 * g);
            float4 v = *(const float4*)(tr + 32 * ch + 16 + 4 * g);
            PackAB pk;
            pk.w[0] = cvtpk(__builtin_amdgcn_exp2f(u.x * L2E), __builtin_amdgcn_exp2f(u.y * L2E));
            pk.w[1] = cvtpk(__builtin_amdgcn_exp2f(u.z * L2E), __builtin_amdgcn_exp2f(u.w * L2E));
            pk.w[2] = cvtpk(__builtin_amdgcn_exp2f(v.x * L2E), __builtin_amdgcn_exp2f(v.y * L2E));
            pk.w[3] = cvtpk(__builtin_amdgcn_exp2f(v.z * L2E), __builtin_amdgcn_exp2f(v.w * L2E));
            A[mt][ch] = pk.v;
        }
    }
    // B = identity in fragment form (verified rounds 8/10)
    PackAB Bf[2][4];
    #pragma unroll
    for (int ch = 0; ch < 2; ++ch)
        #pragma unroll
        for (int nt = 0; nt < 4; ++nt)
            #pragma unroll
            for (int qq = 0; qq < 4; ++qq) {
                int i0 = 2 * qq, i1 = 2 * qq + 1;
                int k0 = 32 * ch + 4 * g + (i0 & 3) + 16 * (i0 >> 2);
                int k1 = 32 * ch + 4 * g + (i1 & 3) + 16 * (i1 >> 2);
                Bf[ch][nt].w[qq] = cvtpk((k0 == 16 * nt + c) ? 1.f : 0.f,
                                         (k1 == 16 * nt + c) ? 1.f : 0.f);
            }

    // 2-deep named x prefetch ring (static indexing only)
    f32x4 XPa[4], XPb[4];
    {
        int t0_ = tbeg + 1;
        int t1_ = tbeg + 2; if (t1_ > segend) t1_ = segend;
        const float* xp0 = xb + (size_t)t0_ * CC + 4 * g;
        const float* xp1 = xb + (size_t)t1_ * CC + 4 * g;
        #pragma unroll
        for (int mt = 0; mt < 4; ++mt) {
            XPa[mt] = *(const f32x4*)(xp0 + 16 * mt);
            XPb[mt] = *(const f32x4*)(xp1 + 16 * mt);
        }
    }

    float Lseg = 0.f, prevS0 = 1.0f;   // first step: r=1, log2=0
    int idx = 0;
    while (true) {
        chain_step(A, Bf, XPa, xb, tbeg, segend, idx, g, prevS0, Lseg);
        if (++idx >= nsteps) break;
        chain_step(A, Bf, XPb, xb, tbeg, segend, idx, g, prevS0, Lseg);
        if (++idx >= nsteps) break;
    }

    // store M_s as bf16 row-major [row][col] (scattered ushort, amortized)
    unsigned short* Mo = Mws + (size_t)blk * 4096;
    #pragma unroll
    for (int ch = 0; ch < 2; ++ch)
        #pragma unroll
        for (int nt = 0; nt < 4; ++nt)
            #pragma unroll
            for (int e = 0; e < 8; ++e) {
                unsigned wb = (unsigned)Bf[ch][nt].w[e >> 1];
                unsigned short hb = (e & 1) ? (unsigned short)(wb >> 16)
                                            : (unsigned short)(wb & 0xffffu);
                int row = 32 * ch + 4 * g + (e & 3) + 16 * (e >> 2);
                Mo[row * 64 + 16 * nt + c] = hb;
            }
    if (l == 0) Ls[blk] = Lseg;
}

__launch_bounds__(64, 1)
__global__ void crf_apply_kernel(const float* __restrict__ x,
                                 const float* __restrict__ orig,
                                 const int*   __restrict__ lens,
                                 const unsigned short* __restrict__ Mws,
                                 const float* __restrict__ Ls,
                                 float* __restrict__ out,
                                 int T, int Pseg, int SEG) {
    const int b = blockIdx.x, j = threadIdx.x;
    __shared__ float qb[CC];
    const float L2E = 1.4426950408889634f, LN2 = 0.6931471805599453f;
    const int L = lens[b];
    const float* xb = x + (size_t)b * T * CC;

    float Mbar = (xb[0] + orig[0]) * L2E;
    float q = __builtin_amdgcn_exp2f((xb[j] + orig[j]) * L2E - Mbar);

    // 1-deep prefetch of this lane's bf16 row (row j of M_s)
    uint4 R[8];
    {
        const uint4* Ms = (const uint4*)(Mws + ((size_t)b * Pseg + 0) * 4096 + j * 64);
        #pragma unroll
        for (int i = 0; i < 8; ++i) R[i] = Ms[i];
    }

    for (int s = 0; s < Pseg; ++s) {
        int tbeg = s * SEG;
        int segend = (s + 1) * SEG; if (segend > L - 1) segend = L - 1;
        if (segend - tbeg <= 0) break;   // later segments inactive too

        uint4 Rc[8];
        #pragma unroll
        for (int i = 0; i < 8; ++i) Rc[i] = R[i];
        {   // prefetch next segment's row (clamped; unused garbage if inactive)
            int s2 = (s + 1 < Pseg) ? s + 1 : s;
            const uint4* Ms = (const uint4*)(Mws + ((size_t)b * Pseg + s2) * 4096 + j * 64);
            #pragma unroll
            for (int i = 0; i < 8; ++i) R[i] = Ms[i];
        }

        qb[j] = q;
        LDS_FENCE();

        float acc = 0.f;
        #pragma unroll
        for (int i = 0; i < 8; ++i) {
            f32x4 qv0 = *(const f32x4*)&qb[8 * i];
            f32x4 qv1 = *(const f32x4*)&qb[8 * i + 4];
            unsigned u0 = Rc[i].x, u1 = Rc[i].y, u2 = Rc[i].z, u3 = Rc[i].w;
            acc = fmaf(__uint_as_float(u0 << 16),        qv0[0], acc);
            acc = fmaf(__uint_as_float(u0 & 0xffff0000), qv0[1], acc);
            acc = fmaf(__uint_as_float(u1 << 16),        qv0[2], acc);
            acc = fmaf(__uint_as_float(u1 & 0xffff0000), qv0[3], acc);
            acc = fmaf(__uint_as_float(u2 << 16),        qv1[0], acc);
            acc = fmaf(__uint_as_float(u2 & 0xffff0000), qv1[1], acc);
            acc = fmaf(__uint_as_float(u3 << 16),        qv1[2], acc);
            acc = fmaf(__uint_as_float(u3 & 0xffff0000), qv1[3], acc);
        }
        float S = acc;
        Mbar += Ls[(size_t)b * Pseg + s];
        float p = bcast0(S);
        float r = __builtin_amdgcn_rcpf(p);
        float lgr = __builtin_amdgcn_logf(r);
        q = S * r;
        Mbar -= lgr;
        LDS_FENCE();   // reads of qb done before next overwrite
    }

    float alpha = LN2 * (Mbar + __builtin_amdgcn_logf(q));
    alpha += __shfl_xor(alpha, 1, 64);
    alpha += __shfl_xor(alpha, 2, 64);
    alpha += __shfl_xor(alpha, 4, 64);
    alpha += __shfl_xor(alpha, 8, 64);
    alpha += __shfl_xor(alpha, 16, 64);
    alpha += __shfl_xor(alpha, 32, 64);
    if (j == 0) out[b] = alpha;
}

extern "C" void kernel_launch(void* const* d_in, const int* in_sizes, int n_in,
                              void* d_out, int out_size, void* d_ws, size_t ws_size,
                              hipStream_t stream) {
    const float* x     = (const float*)d_in[0];
    const float* trans = (const float*)d_in[1];
    const float* orig  = (const float*)d_in[2];
    const int*   lens  = (const int*)d_in[3];
    float* out = (float*)d_out;

    const int B = in_sizes[3];
    const int T = in_sizes[0] / (B * CC);

    int P = 64, Pshift = 6;
    while (P > 1 && ws_size < (size_t)B * P * (4096 * 2 + 4)) { P >>= 1; --Pshift; }
    const int SEG = (T + P - 1) / P;

    unsigned short* Mws = (unsigned short*)d_ws;
    float* Ls = (float*)(Mws + (size_t)B * P * 4096);

    crf_seg_kernel<<<B * P, 64, 0, stream>>>(x, trans, lens, Mws, Ls, T, P, Pshift, SEG);
    crf_apply_kernel<<<B, 64, 0, stream>>>(x, orig, lens, Mws, Ls, out, T, P, SEG);
}